// Round 1
// baseline (481.869 us; speedup 1.0000x reference)
//
#include <hip/hip_runtime.h>

#define NN 8192
#define DD 128
#define BQ 32
#define BK 64
#define NWAVE 8
#define KPW (NN / NWAVE)   // 1024 k per wave
#define NT (KPW / BK)      // 16 tiles per wave

typedef __attribute__((ext_vector_type(8))) short bf16x8;
typedef __attribute__((ext_vector_type(4))) float f32x4;

static __device__ __forceinline__ unsigned short f2bf(float f) {
    union { float f; unsigned u; } v; v.f = f;
    return (unsigned short)((v.u + 0x7FFFu + ((v.u >> 16) & 1u)) >> 16);
}
static __device__ __forceinline__ float bf2f(unsigned short h) {
    union { unsigned u; float f; } v; v.u = ((unsigned)h) << 16;
    return v.f;
}

__global__ __launch_bounds__(512, 2) void attn_fwd(
    const float* __restrict__ Qm, const float* __restrict__ Km,
    const float* __restrict__ Vm, float* __restrict__ out)
{
    const int tid  = threadIdx.x;
    const int wave = tid >> 6;
    const int lane = tid & 63;
    const int c = lane & 15;   // 0..15
    const int g = lane >> 4;   // 0..3
    const int q0 = blockIdx.x * BQ;

    const float LOG2E = 1.44269504088896340736f;

    // ---- Q B-fragments (loop-invariant): scaled by log2e, hi/lo split
    // element jj of frag [qt][ds]: Q[ds*32 + 8g + jj][q0 + qt*16 + c]
    bf16x8 qhi[2][4], qlo[2][4];
    #pragma unroll
    for (int qt = 0; qt < 2; ++qt) {
        #pragma unroll
        for (int ds = 0; ds < 4; ++ds) {
            #pragma unroll
            for (int jj = 0; jj < 8; ++jj) {
                int d = ds * 32 + 8 * g + jj;
                float qv = Qm[(size_t)d * NN + (q0 + qt * 16 + c)] * LOG2E;
                unsigned short h = f2bf(qv);
                qhi[qt][ds][jj] = (short)h;
                qlo[qt][ds][jj] = (short)f2bf(qv - bf2f(h));
            }
        }
    }

    f32x4 acc[2][8];   // O^T frags: [qt][dt], row q=qt*16+4g+r, col d=dt*16+c
    #pragma unroll
    for (int a = 0; a < 2; ++a)
        #pragma unroll
        for (int b = 0; b < 8; ++b)
            acc[a][b] = (f32x4){0.f, 0.f, 0.f, 0.f};

    float mrun[2] = {-INFINITY, -INFINITY};
    float lrun[2] = {0.f, 0.f};

    const int kw0 = wave * KPW;

    for (int t = 0; t < NT; ++t) {
        const int k0 = kw0 + t * BK;

        // ---- MFMA1: T = K_tile^T * Q_tile (S^T), 3-term hi/lo split
        // T[mkt][qt]: lane holds k = k0+mkt*16+4g+r, q = q0+qt*16+c
        f32x4 T[4][2];
        #pragma unroll
        for (int mkt = 0; mkt < 4; ++mkt) {
            T[mkt][0] = (f32x4){0.f, 0.f, 0.f, 0.f};
            T[mkt][1] = (f32x4){0.f, 0.f, 0.f, 0.f};
        }
        #pragma unroll
        for (int mkt = 0; mkt < 4; ++mkt) {
            const int kc = k0 + mkt * 16 + c;
            #pragma unroll
            for (int ds = 0; ds < 4; ++ds) {
                bf16x8 khi, klo;
                #pragma unroll
                for (int jj = 0; jj < 8; ++jj) {
                    int d = ds * 32 + 8 * g + jj;
                    float kv = Km[(size_t)d * NN + kc];
                    unsigned short h = f2bf(kv);
                    khi[jj] = (short)h;
                    klo[jj] = (short)f2bf(kv - bf2f(h));
                }
                #pragma unroll
                for (int qt = 0; qt < 2; ++qt) {
                    T[mkt][qt] = __builtin_amdgcn_mfma_f32_16x16x32_bf16(khi, qhi[qt][ds], T[mkt][qt], 0, 0, 0);
                    T[mkt][qt] = __builtin_amdgcn_mfma_f32_16x16x32_bf16(khi, qlo[qt][ds], T[mkt][qt], 0, 0, 0);
                    T[mkt][qt] = __builtin_amdgcn_mfma_f32_16x16x32_bf16(klo, qhi[qt][ds], T[mkt][qt], 0, 0, 0);
                }
            }
        }

        // ---- online softmax (per wave); pack P into PV A-fragments
        bf16x8 pfrag[2][2];   // [qt][chunk s]: elems 0..3 = subtile 2s, 4..7 = 2s+1
        float scl[2];
        #pragma unroll
        for (int qt = 0; qt < 2; ++qt) {
            float tmax = T[0][qt][0];
            #pragma unroll
            for (int mkt = 0; mkt < 4; ++mkt)
                #pragma unroll
                for (int r = 0; r < 4; ++r)
                    tmax = fmaxf(tmax, T[mkt][qt][r]);
            tmax = fmaxf(tmax, __shfl_xor(tmax, 16, 64));
            tmax = fmaxf(tmax, __shfl_xor(tmax, 32, 64));
            float mnew = fmaxf(mrun[qt], tmax);
            float sc = __builtin_amdgcn_exp2f(mrun[qt] - mnew);
            mrun[qt] = mnew;
            lrun[qt] *= sc;
            scl[qt] = sc;
            #pragma unroll
            for (int s = 0; s < 2; ++s) {
                #pragma unroll
                for (int hf = 0; hf < 2; ++hf) {
                    int mkt = 2 * s + hf;
                    #pragma unroll
                    for (int r = 0; r < 4; ++r) {
                        float p = __builtin_amdgcn_exp2f(T[mkt][qt][r] - mnew);
                        unsigned short pb = f2bf(p);
                        lrun[qt] += bf2f(pb);     // keep l consistent with bf16 P
                        pfrag[qt][s][hf * 4 + r] = (short)pb;
                    }
                }
            }
        }

        // ---- rescale O accumulators (scale lives at lanes c=q; O rows are 4g+r)
        #pragma unroll
        for (int qt = 0; qt < 2; ++qt) {
            #pragma unroll
            for (int r = 0; r < 4; ++r) {
                float f = __shfl(scl[qt], 4 * g + r, 64);
                #pragma unroll
                for (int dt = 0; dt < 8; ++dt)
                    acc[qt][dt][r] *= f;
            }
        }

        // ---- PV: O^T += P * V^T, k-permuted 16x16x32
        // hw kk=8g+jj  <->  actual k: jj<4: 32s+4g+jj ; jj>=4: 32s+16+4g+(jj-4)
        #pragma unroll
        for (int s = 0; s < 2; ++s) {
            #pragma unroll
            for (int dt = 0; dt < 8; ++dt) {
                const float* vp = Vm + (size_t)(dt * 16 + c) * NN + (k0 + 32 * s + 4 * g);
                f32x4 v0 = *(const f32x4*)vp;
                f32x4 v1 = *(const f32x4*)(vp + 16);
                bf16x8 vb;
                #pragma unroll
                for (int e = 0; e < 4; ++e) {
                    vb[e]     = (short)f2bf(v0[e]);
                    vb[4 + e] = (short)f2bf(v1[e]);
                }
                #pragma unroll
                for (int qt = 0; qt < 2; ++qt)
                    acc[qt][dt] = __builtin_amdgcn_mfma_f32_16x16x32_bf16(pfrag[qt][s], vb, acc[qt][dt], 0, 0, 0);
            }
        }
    }

    // ---- cross-wave combine (waves hold disjoint k partials) ----
    __shared__ float obuf[BQ][DD + 4];
    __shared__ float mbuf[NWAVE][BQ];
    __shared__ float lbuf[NWAVE][BQ];
    __shared__ float lsbuf[BQ];

    #pragma unroll
    for (int qt = 0; qt < 2; ++qt) {
        lrun[qt] += __shfl_xor(lrun[qt], 16, 64);
        lrun[qt] += __shfl_xor(lrun[qt], 32, 64);
    }
    if (lane < 16) {
        mbuf[wave][c]      = mrun[0];
        mbuf[wave][16 + c] = mrun[1];
        lbuf[wave][c]      = lrun[0];
        lbuf[wave][16 + c] = lrun[1];
    }
    for (int i = tid; i < BQ * (DD + 4); i += 512)
        (&obuf[0][0])[i] = 0.f;
    __syncthreads();

    float fac[2];
    {
        float lst[2];
        #pragma unroll
        for (int qt = 0; qt < 2; ++qt) {
            int q = qt * 16 + c;
            float mm = -INFINITY;
            #pragma unroll
            for (int w = 0; w < NWAVE; ++w) mm = fmaxf(mm, mbuf[w][q]);
            float ls = 0.f;
            #pragma unroll
            for (int w = 0; w < NWAVE; ++w)
                ls += __builtin_amdgcn_exp2f(mbuf[w][q] - mm) * lbuf[w][q];
            fac[qt] = __builtin_amdgcn_exp2f(mrun[qt] - mm);
            lst[qt] = ls;
        }
        if (wave == 0 && lane < 16) {
            lsbuf[c]      = lst[0];
            lsbuf[16 + c] = lst[1];
        }
    }
    float facr[2][4];
    #pragma unroll
    for (int qt = 0; qt < 2; ++qt)
        #pragma unroll
        for (int r = 0; r < 4; ++r)
            facr[qt][r] = __shfl(fac[qt], 4 * g + r, 64);

    for (int w = 0; w < NWAVE; ++w) {
        if (wave == w) {
            #pragma unroll
            for (int qt = 0; qt < 2; ++qt)
                #pragma unroll
                for (int dt = 0; dt < 8; ++dt)
                    #pragma unroll
                    for (int r = 0; r < 4; ++r)
                        obuf[qt * 16 + 4 * g + r][dt * 16 + c] += facr[qt][r] * acc[qt][dt][r];
        }
        __syncthreads();
    }

    const int qq = tid & 31;
    const int dg = tid >> 5;
    const float inv = 1.f / lsbuf[qq];
    #pragma unroll
    for (int i = 0; i < 8; ++i) {
        int d = dg * 8 + i;
        out[(size_t)d * NN + q0 + qq] = obuf[qq][d] * inv;
    }
}

extern "C" void kernel_launch(void* const* d_in, const int* in_sizes, int n_in,
                              void* d_out, int out_size, void* d_ws, size_t ws_size,
                              hipStream_t stream) {
    const float* Q = (const float*)d_in[0];
    const float* K = (const float*)d_in[1];
    const float* V = (const float*)d_in[2];
    float* out = (float*)d_out;
    dim3 grid(NN / BQ);   // 256 workgroups
    dim3 block(512);      // 8 waves
    hipLaunchKernelGGL(attn_fwd, grid, block, 0, stream, Q, K, V, out);
}

// Round 2
// 96.717 us; speedup vs baseline: 4.9823x; 4.9823x over previous
//
#include <hip/hip_runtime.h>

#define NN 8192
#define DD 128
#define KSPLIT 8
#define KCHUNK (NN / KSPLIT)      // 1024 k per WG
#define BK 32
#define NT (KCHUNK / BK)          // 32 tiles per WG
#define NTILES (NN / BK)          // 256 tiles total
#define TILE_B 24576              // Khi 8K | Klo 8K | Vp 8K
#define OFF_KLO 8192
#define OFF_V 16384
#define WAVES 8
#define BQW 32
#define BQ (WAVES * BQW)          // 256 q per WG

// ws layout
#define WS_M   ((size_t)NTILES * TILE_B)               // 6,291,456
#define WS_L   (WS_M + (size_t)KSPLIT * NN * 4)
#define WS_OP  (WS_L + (size_t)KSPLIT * NN * 4)
#define WS_NEED (WS_OP + (size_t)KSPLIT * NN * DD * 4) // 40,370,176

typedef __attribute__((ext_vector_type(8))) short bf16x8;
typedef __attribute__((ext_vector_type(4))) float f32x4;

static __device__ __forceinline__ unsigned short f2bf(float f) {
    union { float f; unsigned u; } v; v.f = f;
    return (unsigned short)((v.u + 0x7FFFu + ((v.u >> 16) & 1u)) >> 16);
}
static __device__ __forceinline__ float bf2f(unsigned short h) {
    union { unsigned u; float f; } v; v.u = ((unsigned)h) << 16;
    return v.f;
}
static __device__ __forceinline__ void gld_lds16(const char* g, char* l) {
    __builtin_amdgcn_global_load_lds(
        (const __attribute__((address_space(1))) unsigned*)g,
        (__attribute__((address_space(3))) unsigned*)l,
        16, 0, 0);
}

// ---------------- prep: build swizzled bf16 tile images ----------------
__global__ __launch_bounds__(256) void attn_prep(
    const float* __restrict__ Km, const float* __restrict__ Vm,
    char* __restrict__ kst)
{
    __shared__ __align__(16) char img[TILE_B];
    const int tt = blockIdx.x;
    const int tid = threadIdx.x;
    const int k0 = tt * BK;
    // K hi/lo: logical [k][d] bf16, row 256B, swizzle ^((k&7)<<4)
    #pragma unroll
    for (int i = 0; i < 16; ++i) {
        int idx = i * 256 + tid;
        int d = idx >> 5, k = idx & 31;
        float kv = Km[(size_t)d * NN + k0 + k];
        unsigned short hi = f2bf(kv);
        unsigned short lo = f2bf(kv - bf2f(hi));
        int b = (k * 256 + d * 2) ^ ((k & 7) << 4);
        *(unsigned short*)(img + b) = hi;
        *(unsigned short*)(img + OFF_KLO + b) = lo;
    }
    // V: logical [d][j] bf16, row 64B; j = g*8+e maps k = (e<4 ? 4g+e : 16+4g+e-4)
    #pragma unroll
    for (int i = 0; i < 16; ++i) {
        int idx = i * 256 + tid;
        int d = idx >> 5, j = idx & 31;
        int gg = j >> 3, e = j & 7;
        int kl = (e < 4) ? (4 * gg + e) : (16 + 4 * gg + (e - 4));
        float vv = Vm[(size_t)d * NN + k0 + kl];
        int b = (d * 64 + j * 2) ^ ((d & 7) << 4);
        *(unsigned short*)(img + OFF_V + b) = f2bf(vv);
    }
    __syncthreads();
    float4* dst = (float4*)(kst + (size_t)tt * TILE_B);
    const float4* src = (const float4*)img;
    for (int i = tid; i < TILE_B / 16; i += 256) dst[i] = src[i];
}

// ---------------- main: flash attention, split-k partials ----------------
__global__ __launch_bounds__(512, 2) void attn_main(
    const float* __restrict__ Qm, const char* __restrict__ kst,
    float* __restrict__ mArr, float* __restrict__ lArr,
    float* __restrict__ opart)
{
    __shared__ __align__(16) char smem[2 * TILE_B];   // 48KB double buffer
    const int tid = threadIdx.x;
    const int wave = tid >> 6, lane = tid & 63;
    const int c = lane & 15, g = lane >> 4;
    const int ks = blockIdx.x & 7;
    const int qb = blockIdx.x >> 3;
    const int q0w = qb * BQ + wave * BQW;
    const float LOG2E = 1.44269504088896340736f;

    // Q fragments (loop-invariant), scaled by log2e, hi/lo split
    bf16x8 qhi[2][4], qlo[2][4];
    #pragma unroll
    for (int qt = 0; qt < 2; ++qt)
        #pragma unroll
        for (int ds = 0; ds < 4; ++ds)
            #pragma unroll
            for (int jj = 0; jj < 8; ++jj) {
                int d = ds * 32 + 8 * g + jj;
                float qv = Qm[(size_t)d * NN + (q0w + qt * 16 + c)] * LOG2E;
                unsigned short h = f2bf(qv);
                qhi[qt][ds][jj] = (short)h;
                qlo[qt][ds][jj] = (short)f2bf(qv - bf2f(h));
            }

    f32x4 acc[2][8];
    #pragma unroll
    for (int a = 0; a < 2; ++a)
        #pragma unroll
        for (int b = 0; b < 8; ++b)
            acc[a][b] = (f32x4){0.f, 0.f, 0.f, 0.f};
    float mrun[2] = {-INFINITY, -INFINITY};
    float lrun[2] = {0.f, 0.f};

    // stage tile 0 → buf 0
    {
        const char* gsrc = kst + (size_t)(ks * NT) * TILE_B + wave * 3072 + lane * 16;
        char* ldst = smem + wave * 3072 + lane * 16;
        #pragma unroll
        for (int i = 0; i < 3; ++i) gld_lds16(gsrc + i * 1024, ldst + i * 1024);
    }
    __syncthreads();

    for (int t = 0; t < NT; ++t) {
        const int cur = t & 1;
        const char* kb = smem + cur * TILE_B;

        if (t + 1 < NT) {   // prefetch next tile into other buffer
            const char* gsrc = kst + (size_t)(ks * NT + t + 1) * TILE_B + wave * 3072 + lane * 16;
            char* ldst = smem + (cur ^ 1) * TILE_B + wave * 3072 + lane * 16;
            #pragma unroll
            for (int i = 0; i < 3; ++i) gld_lds16(gsrc + i * 1024, ldst + i * 1024);
        }

        // QK^T (S^T), 3-term hi/lo split: T[mkt][qt], k=mkt*16+4g+r, q=qt*16+c
        f32x4 T[2][2];
        #pragma unroll
        for (int mkt = 0; mkt < 2; ++mkt) {
            T[mkt][0] = (f32x4){0.f, 0.f, 0.f, 0.f};
            T[mkt][1] = (f32x4){0.f, 0.f, 0.f, 0.f};
        }
        #pragma unroll
        for (int mkt = 0; mkt < 2; ++mkt) {
            int k = mkt * 16 + c;
            int rowoff = k * 256;
            int swz = (k & 7) << 4;
            #pragma unroll
            for (int ds = 0; ds < 4; ++ds) {
                int off = (rowoff + ds * 64 + g * 16) ^ swz;
                bf16x8 khi = *(const bf16x8*)(kb + off);
                bf16x8 klo = *(const bf16x8*)(kb + OFF_KLO + off);
                #pragma unroll
                for (int qt = 0; qt < 2; ++qt) {
                    T[mkt][qt] = __builtin_amdgcn_mfma_f32_16x16x32_bf16(khi, qhi[qt][ds], T[mkt][qt], 0, 0, 0);
                    T[mkt][qt] = __builtin_amdgcn_mfma_f32_16x16x32_bf16(khi, qlo[qt][ds], T[mkt][qt], 0, 0, 0);
                    T[mkt][qt] = __builtin_amdgcn_mfma_f32_16x16x32_bf16(klo, qhi[qt][ds], T[mkt][qt], 0, 0, 0);
                }
            }
        }

        // online softmax; pack P into PV A-frag (hw kk=8g+jj ↔ k=16hf+4g+r)
        bf16x8 pfrag[2];
        float scl[2];
        #pragma unroll
        for (int qt = 0; qt < 2; ++qt) {
            float tmax = T[0][qt][0];
            #pragma unroll
            for (int mkt = 0; mkt < 2; ++mkt)
                #pragma unroll
                for (int r = 0; r < 4; ++r)
                    tmax = fmaxf(tmax, T[mkt][qt][r]);
            tmax = fmaxf(tmax, __shfl_xor(tmax, 16, 64));
            tmax = fmaxf(tmax, __shfl_xor(tmax, 32, 64));
            float mnew = fmaxf(mrun[qt], tmax);
            float sc = __builtin_amdgcn_exp2f(mrun[qt] - mnew);
            mrun[qt] = mnew;
            lrun[qt] *= sc;
            scl[qt] = sc;
            #pragma unroll
            for (int hf = 0; hf < 2; ++hf)
                #pragma unroll
                for (int r = 0; r < 4; ++r) {
                    float p = __builtin_amdgcn_exp2f(T[hf][qt][r] - mnew);
                    unsigned short pb = f2bf(p);
                    lrun[qt] += bf2f(pb);
                    pfrag[qt][hf * 4 + r] = (short)pb;
                }
        }

        // rescale O accumulators
        #pragma unroll
        for (int qt = 0; qt < 2; ++qt)
            #pragma unroll
            for (int r = 0; r < 4; ++r) {
                float f = __shfl(scl[qt], 4 * g + r, 64);
                #pragma unroll
                for (int dt = 0; dt < 8; ++dt)
                    acc[qt][dt][r] *= f;
            }

        // PV: O^T += P * V^T
        #pragma unroll
        for (int dt = 0; dt < 8; ++dt) {
            int d = dt * 16 + c;
            int off = (d * 64 + g * 16) ^ ((d & 7) << 4);
            bf16x8 vb = *(const bf16x8*)(kb + OFF_V + off);
            #pragma unroll
            for (int qt = 0; qt < 2; ++qt)
                acc[qt][dt] = __builtin_amdgcn_mfma_f32_16x16x32_bf16(pfrag[qt], vb, acc[qt][dt], 0, 0, 0);
        }

        __syncthreads();
    }

    // epilogue: per-wave partials to ws (waves own disjoint q)
    #pragma unroll
    for (int qt = 0; qt < 2; ++qt) {
        lrun[qt] += __shfl_xor(lrun[qt], 16, 64);
        lrun[qt] += __shfl_xor(lrun[qt], 32, 64);
    }
    if (lane < 16) {
        #pragma unroll
        for (int qt = 0; qt < 2; ++qt) {
            int q = q0w + qt * 16 + c;
            mArr[ks * NN + q] = mrun[qt];
            lArr[ks * NN + q] = lrun[qt];
        }
    }
    #pragma unroll
    for (int qt = 0; qt < 2; ++qt)
        #pragma unroll
        for (int dt = 0; dt < 8; ++dt)
            #pragma unroll
            for (int r = 0; r < 4; ++r) {
                int q = q0w + qt * 16 + 4 * g + r;
                opart[((size_t)ks * NN + q) * DD + dt * 16 + c] = acc[qt][dt][r];
            }
}

// ---------------- combine: merge split-k partials ----------------
__global__ __launch_bounds__(256) void attn_combine(
    const float* __restrict__ opart, const float* __restrict__ mArr,
    const float* __restrict__ lArr, float* __restrict__ out)
{
    __shared__ float tr[DD * 65];
    const int tid = threadIdx.x;
    const int q0 = blockIdx.x * 64;
    const int ql = tid >> 2;
    const int dseg = (tid & 3) * 32;
    const int q = q0 + ql;

    float m[KSPLIT], l[KSPLIT], w[KSPLIT];
    float M = -INFINITY;
    #pragma unroll
    for (int s = 0; s < KSPLIT; ++s) {
        m[s] = mArr[s * NN + q];
        l[s] = lArr[s * NN + q];
        M = fmaxf(M, m[s]);
    }
    float L = 0.f;
    #pragma unroll
    for (int s = 0; s < KSPLIT; ++s) {
        w[s] = __builtin_amdgcn_exp2f(m[s] - M);
        L += w[s] * l[s];
    }
    float invL = 1.f / L;

    float a[32];
    #pragma unroll
    for (int j = 0; j < 32; ++j) a[j] = 0.f;
    for (int s = 0; s < KSPLIT; ++s) {
        const float* p = opart + ((size_t)s * NN + q) * DD + dseg;
        float ws = w[s] * invL;
        #pragma unroll
        for (int jc = 0; jc < 8; ++jc) {
            f32x4 v = *(const f32x4*)(p + jc * 4);
            #pragma unroll
            for (int e = 0; e < 4; ++e) a[jc * 4 + e] += ws * v[e];
        }
    }
    #pragma unroll
    for (int j = 0; j < 32; ++j) tr[(dseg + j) * 65 + ql] = a[j];
    __syncthreads();
    const int lane2 = tid & 63, grp = tid >> 6;
    #pragma unroll
    for (int j = 0; j < 32; ++j) {
        int d = grp * 32 + j;
        out[(size_t)d * NN + q0 + lane2] = tr[d * 65 + lane2];
    }
}

// ---------------- fallback (round-1 kernel, used if ws too small) ----------------
__global__ __launch_bounds__(512, 2) void attn_fwd_fb(
    const float* __restrict__ Qm, const float* __restrict__ Km,
    const float* __restrict__ Vm, float* __restrict__ out)
{
    const int tid  = threadIdx.x;
    const int wave = tid >> 6;
    const int lane = tid & 63;
    const int c = lane & 15;
    const int g = lane >> 4;
    const int q0 = blockIdx.x * 32;
    const float LOG2E = 1.44269504088896340736f;

    bf16x8 qhi[2][4], qlo[2][4];
    #pragma unroll
    for (int qt = 0; qt < 2; ++qt)
        #pragma unroll
        for (int ds = 0; ds < 4; ++ds)
            #pragma unroll
            for (int jj = 0; jj < 8; ++jj) {
                int d = ds * 32 + 8 * g + jj;
                float qv = Qm[(size_t)d * NN + (q0 + qt * 16 + c)] * LOG2E;
                unsigned short h = f2bf(qv);
                qhi[qt][ds][jj] = (short)h;
                qlo[qt][ds][jj] = (short)f2bf(qv - bf2f(h));
            }

    f32x4 acc[2][8];
    #pragma unroll
    for (int a = 0; a < 2; ++a)
        #pragma unroll
        for (int b = 0; b < 8; ++b)
            acc[a][b] = (f32x4){0.f, 0.f, 0.f, 0.f};
    float mrun[2] = {-INFINITY, -INFINITY};
    float lrun[2] = {0.f, 0.f};
    const int kw0 = wave * (NN / 8);

    for (int t = 0; t < (NN / 8) / 64; ++t) {
        const int k0 = kw0 + t * 64;
        f32x4 T[4][2];
        #pragma unroll
        for (int mkt = 0; mkt < 4; ++mkt) {
            T[mkt][0] = (f32x4){0.f, 0.f, 0.f, 0.f};
            T[mkt][1] = (f32x4){0.f, 0.f, 0.f, 0.f};
        }
        #pragma unroll
        for (int mkt = 0; mkt < 4; ++mkt) {
            const int kc = k0 + mkt * 16 + c;
            #pragma unroll
            for (int ds = 0; ds < 4; ++ds) {
                bf16x8 khi, klo;
                #pragma unroll
                for (int jj = 0; jj < 8; ++jj) {
                    int d = ds * 32 + 8 * g + jj;
                    float kv = Km[(size_t)d * NN + kc];
                    unsigned short h = f2bf(kv);
                    khi[jj] = (short)h;
                    klo[jj] = (short)f2bf(kv - bf2f(h));
                }
                #pragma unroll
                for (int qt = 0; qt < 2; ++qt) {
                    T[mkt][qt] = __builtin_amdgcn_mfma_f32_16x16x32_bf16(khi, qhi[qt][ds], T[mkt][qt], 0, 0, 0);
                    T[mkt][qt] = __builtin_amdgcn_mfma_f32_16x16x32_bf16(khi, qlo[qt][ds], T[mkt][qt], 0, 0, 0);
                    T[mkt][qt] = __builtin_amdgcn_mfma_f32_16x16x32_bf16(klo, qhi[qt][ds], T[mkt][qt], 0, 0, 0);
                }
            }
        }
        bf16x8 pfrag[2][2];
        float scl[2];
        #pragma unroll
        for (int qt = 0; qt < 2; ++qt) {
            float tmax = T[0][qt][0];
            #pragma unroll
            for (int mkt = 0; mkt < 4; ++mkt)
                #pragma unroll
                for (int r = 0; r < 4; ++r)
                    tmax = fmaxf(tmax, T[mkt][qt][r]);
            tmax = fmaxf(tmax, __shfl_xor(tmax, 16, 64));
            tmax = fmaxf(tmax, __shfl_xor(tmax, 32, 64));
            float mnew = fmaxf(mrun[qt], tmax);
            float sc = __builtin_amdgcn_exp2f(mrun[qt] - mnew);
            mrun[qt] = mnew;
            lrun[qt] *= sc;
            scl[qt] = sc;
            #pragma unroll
            for (int s = 0; s < 2; ++s)
                #pragma unroll
                for (int hf = 0; hf < 2; ++hf) {
                    int mkt = 2 * s + hf;
                    #pragma unroll
                    for (int r = 0; r < 4; ++r) {
                        float p = __builtin_amdgcn_exp2f(T[mkt][qt][r] - mnew);
                        unsigned short pb = f2bf(p);
                        lrun[qt] += bf2f(pb);
                        pfrag[qt][s][hf * 4 + r] = (short)pb;
                    }
                }
        }
        #pragma unroll
        for (int qt = 0; qt < 2; ++qt)
            #pragma unroll
            for (int r = 0; r < 4; ++r) {
                float f = __shfl(scl[qt], 4 * g + r, 64);
                #pragma unroll
                for (int dt = 0; dt < 8; ++dt)
                    acc[qt][dt][r] *= f;
            }
        #pragma unroll
        for (int s = 0; s < 2; ++s)
            #pragma unroll
            for (int dt = 0; dt < 8; ++dt) {
                const float* vp = Vm + (size_t)(dt * 16 + c) * NN + (k0 + 32 * s + 4 * g);
                f32x4 v0 = *(const f32x4*)vp;
                f32x4 v1 = *(const f32x4*)(vp + 16);
                bf16x8 vb;
                #pragma unroll
                for (int e = 0; e < 4; ++e) {
                    vb[e]     = (short)f2bf(v0[e]);
                    vb[4 + e] = (short)f2bf(v1[e]);
                }
                #pragma unroll
                for (int qt = 0; qt < 2; ++qt)
                    acc[qt][dt] = __builtin_amdgcn_mfma_f32_16x16x32_bf16(pfrag[qt][s], vb, acc[qt][dt], 0, 0, 0);
            }
    }

    __shared__ float obuf[32][DD + 4];
    __shared__ float mbuf[8][32];
    __shared__ float lbuf[8][32];
    __shared__ float lsbuf[32];
    #pragma unroll
    for (int qt = 0; qt < 2; ++qt) {
        lrun[qt] += __shfl_xor(lrun[qt], 16, 64);
        lrun[qt] += __shfl_xor(lrun[qt], 32, 64);
    }
    if (lane < 16) {
        mbuf[wave][c]      = mrun[0];
        mbuf[wave][16 + c] = mrun[1];
        lbuf[wave][c]      = lrun[0];
        lbuf[wave][16 + c] = lrun[1];
    }
    for (int i = tid; i < 32 * (DD + 4); i += 512)
        (&obuf[0][0])[i] = 0.f;
    __syncthreads();
    float fac[2];
    {
        float lst[2];
        #pragma unroll
        for (int qt = 0; qt < 2; ++qt) {
            int q = qt * 16 + c;
            float mm = -INFINITY;
            #pragma unroll
            for (int w = 0; w < 8; ++w) mm = fmaxf(mm, mbuf[w][q]);
            float ls = 0.f;
            #pragma unroll
            for (int w = 0; w < 8; ++w)
                ls += __builtin_amdgcn_exp2f(mbuf[w][q] - mm) * lbuf[w][q];
            fac[qt] = __builtin_amdgcn_exp2f(mrun[qt] - mm);
            lst[qt] = ls;
        }
        if (wave == 0 && lane < 16) {
            lsbuf[c]      = lst[0];
            lsbuf[16 + c] = lst[1];
        }
    }
    float facr[2][4];
    #pragma unroll
    for (int qt = 0; qt < 2; ++qt)
        #pragma unroll
        for (int r = 0; r < 4; ++r)
            facr[qt][r] = __shfl(fac[qt], 4 * g + r, 64);
    for (int w = 0; w < 8; ++w) {
        if (wave == w) {
            #pragma unroll
            for (int qt = 0; qt < 2; ++qt)
                #pragma unroll
                for (int dt = 0; dt < 8; ++dt)
                    #pragma unroll
                    for (int r = 0; r < 4; ++r)
                        obuf[qt * 16 + 4 * g + r][dt * 16 + c] += facr[qt][r] * acc[qt][dt][r];
        }
        __syncthreads();
    }
    const int qq = tid & 31;
    const int dg = tid >> 5;
    const float inv = 1.f / lsbuf[qq];
    #pragma unroll
    for (int i = 0; i < 8; ++i) {
        int d = dg * 8 + i;
        out[(size_t)d * NN + q0 + qq] = obuf[qq][d] * inv;
    }
}

extern "C" void kernel_launch(void* const* d_in, const int* in_sizes, int n_in,
                              void* d_out, int out_size, void* d_ws, size_t ws_size,
                              hipStream_t stream) {
    const float* Q = (const float*)d_in[0];
    const float* K = (const float*)d_in[1];
    const float* V = (const float*)d_in[2];
    float* out = (float*)d_out;

    if (ws_size < WS_NEED || d_ws == nullptr) {
        hipLaunchKernelGGL(attn_fwd_fb, dim3(NN / 32), dim3(512), 0, stream, Q, K, V, out);
        return;
    }
    char* ws = (char*)d_ws;
    char* kst = ws;
    float* mArr = (float*)(ws + WS_M);
    float* lArr = (float*)(ws + WS_L);
    float* opart = (float*)(ws + WS_OP);

    hipLaunchKernelGGL(attn_prep, dim3(NTILES), dim3(256), 0, stream, K, V, kst);
    hipLaunchKernelGGL(attn_main, dim3(KSPLIT * (NN / BQ)), dim3(512), 0, stream, Q, kst, mArr, lArr, opart);
    hipLaunchKernelGGL(attn_combine, dim3(NN / 64), dim3(256), 0, stream, opart, mArr, lArr, out);
}

// Round 3
// 92.756 us; speedup vs baseline: 5.1950x; 1.0427x over previous
//
#include <hip/hip_runtime.h>

#define NN 8192
#define DD 128
#define KSPLIT 8
#define KCHUNK (NN / KSPLIT)      // 1024 k per WG
#define BK 32
#define NT (KCHUNK / BK)          // 32 tiles per WG
#define NTILES (NN / BK)          // 256 tiles total
#define TILE_B 24576              // Khi 8K | Klo 8K | Vp 8K
#define OFF_KLO 8192
#define OFF_V 16384
#define WAVES 4
#define BQ (WAVES * 32)           // 128 q per WG

// ws layout
#define WS_M   ((size_t)NTILES * TILE_B)
#define WS_L   (WS_M + (size_t)KSPLIT * NN * 4)
#define WS_OP  (WS_L + (size_t)KSPLIT * NN * 4)
#define WS_NEED (WS_OP + (size_t)KSPLIT * NN * DD * 4) // ~40.4 MB

typedef __attribute__((ext_vector_type(8))) short bf16x8;
typedef __attribute__((ext_vector_type(4))) float f32x4;
typedef __attribute__((ext_vector_type(16))) float f32x16;

static __device__ __forceinline__ unsigned short f2bf(float f) {
    union { float f; unsigned u; } v; v.f = f;
    return (unsigned short)((v.u + 0x7FFFu + ((v.u >> 16) & 1u)) >> 16);
}
static __device__ __forceinline__ float bf2f(unsigned short h) {
    union { unsigned u; float f; } v; v.u = ((unsigned)h) << 16;
    return v.f;
}
static __device__ __forceinline__ void gld_lds16(const char* g, char* l) {
    __builtin_amdgcn_global_load_lds(
        (const __attribute__((address_space(1))) unsigned*)g,
        (__attribute__((address_space(3))) unsigned*)l,
        16, 0, 0);
}

// ---------------- prep: build swizzled bf16 tile images ----------------
__global__ __launch_bounds__(256) void attn_prep(
    const float* __restrict__ Km, const float* __restrict__ Vm,
    char* __restrict__ kst)
{
    __shared__ __align__(16) char img[TILE_B];
    const int tt = blockIdx.x;
    const int tid = threadIdx.x;
    const int k0 = tt * BK;
    // K hi/lo: logical [k][d] bf16, row 256B, swizzle ^((k&7)<<4)
    #pragma unroll
    for (int i = 0; i < 16; ++i) {
        int idx = i * 256 + tid;
        int d = idx >> 5, k = idx & 31;
        float kv = Km[(size_t)d * NN + k0 + k];
        unsigned short hi = f2bf(kv);
        unsigned short lo = f2bf(kv - bf2f(hi));
        int b = (k * 256 + d * 2) ^ ((k & 7) << 4);
        *(unsigned short*)(img + b) = hi;
        *(unsigned short*)(img + OFF_KLO + b) = lo;
    }
    // V: logical [d][j] bf16, row 64B, swizzle ^((d&7)<<4)
    // j = s2*16 + h*8 + jj  maps actual k = (jj&3) + 4h + 8*(jj>>2) + 16*s2
    #pragma unroll
    for (int i = 0; i < 16; ++i) {
        int idx = i * 256 + tid;
        int d = idx >> 5, j = idx & 31;
        int kl = (j & 3) + 4 * ((j >> 3) & 1) + 8 * ((j >> 2) & 1) + 16 * (j >> 4);
        float vv = Vm[(size_t)d * NN + k0 + kl];
        int b = (d * 64 + j * 2) ^ ((d & 7) << 4);
        *(unsigned short*)(img + OFF_V + b) = f2bf(vv);
    }
    __syncthreads();
    float4* dst = (float4*)(kst + (size_t)tt * TILE_B);
    const float4* src = (const float4*)img;
    for (int i = tid; i < TILE_B / 16; i += 256) dst[i] = src[i];
}

// ---------------- main: flash attention, 32x32 MFMA, split-k ----------------
__global__ __launch_bounds__(256, 2) void attn_main(
    const float* __restrict__ Qm, const char* __restrict__ kst,
    float* __restrict__ mArr, float* __restrict__ lArr,
    float* __restrict__ opart)
{
    __shared__ __align__(16) char smem[2 * TILE_B];   // 48KB double buffer
    const int tid = threadIdx.x;
    const int wave = tid >> 6, lane = tid & 63;
    const int q31 = lane & 31;          // q col (B/D), k row (A-QK), d row (A-PV)
    const int h = lane >> 5;
    const int swz = (lane & 7) << 4;
    const int ks = blockIdx.x & 7;
    const int qb = blockIdx.x >> 3;
    const int q0w = qb * BQ + wave * 32;
    const int qg = q0w + q31;
    const float LOG2E = 1.44269504088896340736f;

    // Q B-fragments: elem jj of qhi/qlo[ds] = Q[16ds+8h+jj][qg]*log2e, hi/lo split
    bf16x8 qhi[8], qlo[8];
    #pragma unroll
    for (int ds = 0; ds < 8; ++ds)
        #pragma unroll
        for (int jj = 0; jj < 8; ++jj) {
            int d = 16 * ds + 8 * h + jj;
            float qv = Qm[(size_t)d * NN + qg] * LOG2E;
            unsigned short hv = f2bf(qv);
            qhi[ds][jj] = (short)hv;
            qlo[ds][jj] = (short)f2bf(qv - bf2f(hv));
        }

    f32x16 acc[4];
    #pragma unroll
    for (int dt = 0; dt < 4; ++dt)
        #pragma unroll
        for (int r = 0; r < 16; ++r) acc[dt][r] = 0.f;
    float mrun = -INFINITY, lrun = 0.f;

    // stage tile 0 -> buf 0
    {
        const char* gsrc = kst + (size_t)(ks * NT) * TILE_B + tid * 16;
        char* ldst = smem + tid * 16;
        #pragma unroll
        for (int i = 0; i < 6; ++i) gld_lds16(gsrc + i * 4096, ldst + i * 4096);
    }
    __syncthreads();

    for (int t = 0; t < NT; ++t) {
        const int cur = t & 1;
        const char* kb = smem + cur * TILE_B;

        if (t + 1 < NT) {   // prefetch next tile into other buffer
            const char* gsrc = kst + (size_t)(ks * NT + t + 1) * TILE_B + tid * 16;
            char* ldst = smem + (cur ^ 1) * TILE_B + tid * 16;
            #pragma unroll
            for (int i = 0; i < 6; ++i) gld_lds16(gsrc + i * 4096, ldst + i * 4096);
        }

        // ---- QK^T: S^T[k=32][q=32], 3-term hi/lo, 8 d-steps of 16
        f32x16 T;
        #pragma unroll
        for (int r = 0; r < 16; ++r) T[r] = 0.f;
        #pragma unroll
        for (int ds = 0; ds < 8; ++ds) {
            int off = ((q31 << 8) + ds * 32 + (h << 4)) ^ swz;
            bf16x8 khi = *(const bf16x8*)(kb + off);
            bf16x8 klo = *(const bf16x8*)(kb + OFF_KLO + off);
            T = __builtin_amdgcn_mfma_f32_32x32x16_bf16(khi, qhi[ds], T, 0, 0, 0);
            T = __builtin_amdgcn_mfma_f32_32x32x16_bf16(khi, qlo[ds], T, 0, 0, 0);
            T = __builtin_amdgcn_mfma_f32_32x32x16_bf16(klo, qhi[ds], T, 0, 0, 0);
        }

        // ---- online softmax (per-lane q; halves combined via xor32)
        float tmax = T[0];
        #pragma unroll
        for (int r = 1; r < 16; ++r) tmax = fmaxf(tmax, T[r]);
        tmax = fmaxf(tmax, __shfl_xor(tmax, 32, 64));
        float mnew = fmaxf(mrun, tmax);
        float sc = __builtin_amdgcn_exp2f(mrun - mnew);
        mrun = mnew;
        lrun *= sc;

        bf16x8 pfrag[2];
        float psum = 0.f;
        #pragma unroll
        for (int s2 = 0; s2 < 2; ++s2)
            #pragma unroll
            for (int jj = 0; jj < 8; ++jj) {
                float p = __builtin_amdgcn_exp2f(T[8 * s2 + jj] - mnew);
                psum += p;
                pfrag[s2][jj] = (short)f2bf(p);
            }
        lrun += psum;

        // ---- rescale O accumulators (per-lane factor, no shuffles)
        #pragma unroll
        for (int dt = 0; dt < 4; ++dt)
            #pragma unroll
            for (int r = 0; r < 16; ++r) acc[dt][r] *= sc;

        // ---- PV: O^T[d][q] += V^T * P  (k-permuted contraction)
        #pragma unroll
        for (int dt = 0; dt < 4; ++dt) {
            int vbase = (dt * 32 + q31) * 64 + (h << 4);
            #pragma unroll
            for (int s2 = 0; s2 < 2; ++s2) {
                bf16x8 vb = *(const bf16x8*)(kb + OFF_V + ((vbase + s2 * 32) ^ swz));
                acc[dt] = __builtin_amdgcn_mfma_f32_32x32x16_bf16(vb, pfrag[s2], acc[dt], 0, 0, 0);
            }
        }

        __syncthreads();
    }

    // ---- epilogue: partials to ws
    lrun += __shfl_xor(lrun, 32, 64);
    if (lane < 32) {
        mArr[ks * NN + q0w + lane] = mrun;
        lArr[ks * NN + q0w + lane] = lrun;
    }
    #pragma unroll
    for (int dt = 0; dt < 4; ++dt)
        #pragma unroll
        for (int r = 0; r < 16; ++r) {
            int d = dt * 32 + (r & 3) + 8 * (r >> 2) + 4 * h;
            opart[((size_t)ks * DD + d) * NN + qg] = acc[dt][r];
        }
}

// ---------------- combine: merge split-k partials ----------------
__global__ __launch_bounds__(256) void attn_combine(
    const float* __restrict__ opart, const float* __restrict__ mArr,
    const float* __restrict__ lArr, float* __restrict__ out)
{
    const int tid = threadIdx.x;
    const int qb = blockIdx.x >> 3;
    const int dseg = (blockIdx.x & 7) * 16;
    const int q = qb * 256 + tid;

    float m[KSPLIT], w[KSPLIT];
    float M = -INFINITY;
    #pragma unroll
    for (int s = 0; s < KSPLIT; ++s) {
        m[s] = mArr[s * NN + q];
        M = fmaxf(M, m[s]);
    }
    float L = 0.f;
    #pragma unroll
    for (int s = 0; s < KSPLIT; ++s) {
        w[s] = __builtin_amdgcn_exp2f(m[s] - M);
        L += w[s] * lArr[s * NN + q];
    }
    float invL = 1.f / L;
    #pragma unroll
    for (int s = 0; s < KSPLIT; ++s) w[s] *= invL;

    for (int dd = 0; dd < 16; ++dd) {
        int d = dseg + dd;
        float a = 0.f;
        #pragma unroll
        for (int s = 0; s < KSPLIT; ++s)
            a += w[s] * opart[((size_t)s * DD + d) * NN + q];
        out[(size_t)d * NN + q] = a;
    }
}

// ---------------- fallback (round-1 kernel, used if ws too small) ----------------
__global__ __launch_bounds__(512, 2) void attn_fwd_fb(
    const float* __restrict__ Qm, const float* __restrict__ Km,
    const float* __restrict__ Vm, float* __restrict__ out)
{
    const int tid  = threadIdx.x;
    const int wave = tid >> 6;
    const int lane = tid & 63;
    const int c = lane & 15;
    const int g = lane >> 4;
    const int q0 = blockIdx.x * 32;
    const float LOG2E = 1.44269504088896340736f;

    bf16x8 qhi[2][4], qlo[2][4];
    #pragma unroll
    for (int qt = 0; qt < 2; ++qt)
        #pragma unroll
        for (int ds = 0; ds < 4; ++ds)
            #pragma unroll
            for (int jj = 0; jj < 8; ++jj) {
                int d = ds * 32 + 8 * g + jj;
                float qv = Qm[(size_t)d * NN + (q0 + qt * 16 + c)] * LOG2E;
                unsigned short hv = f2bf(qv);
                qhi[qt][ds][jj] = (short)hv;
                qlo[qt][ds][jj] = (short)f2bf(qv - bf2f(hv));
            }

    f32x4 acc[2][8];
    #pragma unroll
    for (int a = 0; a < 2; ++a)
        #pragma unroll
        for (int b = 0; b < 8; ++b)
            acc[a][b] = (f32x4){0.f, 0.f, 0.f, 0.f};
    float mrun[2] = {-INFINITY, -INFINITY};
    float lrun[2] = {0.f, 0.f};
    const int kw0 = wave * (NN / 8);

    for (int t = 0; t < (NN / 8) / 64; ++t) {
        const int k0 = kw0 + t * 64;
        f32x4 T[4][2];
        #pragma unroll
        for (int mkt = 0; mkt < 4; ++mkt) {
            T[mkt][0] = (f32x4){0.f, 0.f, 0.f, 0.f};
            T[mkt][1] = (f32x4){0.f, 0.f, 0.f, 0.f};
        }
        #pragma unroll
        for (int mkt = 0; mkt < 4; ++mkt) {
            const int kc = k0 + mkt * 16 + c;
            #pragma unroll
            for (int ds = 0; ds < 4; ++ds) {
                bf16x8 khi, klo;
                #pragma unroll
                for (int jj = 0; jj < 8; ++jj) {
                    int d = ds * 32 + 8 * g + jj;
                    float kv = Km[(size_t)d * NN + kc];
                    unsigned short hv = f2bf(kv);
                    khi[jj] = (short)hv;
                    klo[jj] = (short)f2bf(kv - bf2f(hv));
                }
                #pragma unroll
                for (int qt = 0; qt < 2; ++qt) {
                    T[mkt][qt] = __builtin_amdgcn_mfma_f32_16x16x32_bf16(khi, qhi[qt][ds], T[mkt][qt], 0, 0, 0);
                    T[mkt][qt] = __builtin_amdgcn_mfma_f32_16x16x32_bf16(khi, qlo[qt][ds], T[mkt][qt], 0, 0, 0);
                    T[mkt][qt] = __builtin_amdgcn_mfma_f32_16x16x32_bf16(klo, qhi[qt][ds], T[mkt][qt], 0, 0, 0);
                }
            }
        }
        bf16x8 pfrag[2][2];
        float scl[2];
        #pragma unroll
        for (int qt = 0; qt < 2; ++qt) {
            float tmax = T[0][qt][0];
            #pragma unroll
            for (int mkt = 0; mkt < 4; ++mkt)
                #pragma unroll
                for (int r = 0; r < 4; ++r)
                    tmax = fmaxf(tmax, T[mkt][qt][r]);
            tmax = fmaxf(tmax, __shfl_xor(tmax, 16, 64));
            tmax = fmaxf(tmax, __shfl_xor(tmax, 32, 64));
            float mnew = fmaxf(mrun[qt], tmax);
            float sc = __builtin_amdgcn_exp2f(mrun[qt] - mnew);
            mrun[qt] = mnew;
            lrun[qt] *= sc;
            scl[qt] = sc;
            #pragma unroll
            for (int s = 0; s < 2; ++s)
                #pragma unroll
                for (int hf = 0; hf < 2; ++hf) {
                    int mkt = 2 * s + hf;
                    #pragma unroll
                    for (int r = 0; r < 4; ++r) {
                        float p = __builtin_amdgcn_exp2f(T[mkt][qt][r] - mnew);
                        unsigned short pb = f2bf(p);
                        lrun[qt] += bf2f(pb);
                        pfrag[qt][s][hf * 4 + r] = (short)pb;
                    }
                }
        }
        #pragma unroll
        for (int qt = 0; qt < 2; ++qt)
            #pragma unroll
            for (int r = 0; r < 4; ++r) {
                float f = __shfl(scl[qt], 4 * g + r, 64);
                #pragma unroll
                for (int dt = 0; dt < 8; ++dt)
                    acc[qt][dt][r] *= f;
            }
        #pragma unroll
        for (int s = 0; s < 2; ++s)
            #pragma unroll
            for (int dt = 0; dt < 8; ++dt) {
                const float* vp = Vm + (size_t)(dt * 16 + c) * NN + (k0 + 32 * s + 4 * g);
                f32x4 v0 = *(const f32x4*)vp;
                f32x4 v1 = *(const f32x4*)(vp + 16);
                bf16x8 vb;
                #pragma unroll
                for (int e = 0; e < 4; ++e) {
                    vb[e]     = (short)f2bf(v0[e]);
                    vb[4 + e] = (short)f2bf(v1[e]);
                }
                #pragma unroll
                for (int qt = 0; qt < 2; ++qt)
                    acc[qt][dt] = __builtin_amdgcn_mfma_f32_16x16x32_bf16(pfrag[qt][s], vb, acc[qt][dt], 0, 0, 0);
            }
    }

    __shared__ float obuf[32][DD + 4];
    __shared__ float mbuf[8][32];
    __shared__ float lbuf[8][32];
    __shared__ float lsbuf[32];
    #pragma unroll
    for (int qt = 0; qt < 2; ++qt) {
        lrun[qt] += __shfl_xor(lrun[qt], 16, 64);
        lrun[qt] += __shfl_xor(lrun[qt], 32, 64);
    }
    if (lane < 16) {
        mbuf[wave][c]      = mrun[0];
        mbuf[wave][16 + c] = mrun[1];
        lbuf[wave][c]      = lrun[0];
        lbuf[wave][16 + c] = lrun[1];
    }
    for (int i = tid; i < 32 * (DD + 4); i += 512)
        (&obuf[0][0])[i] = 0.f;
    __syncthreads();
    float fac[2];
    {
        float lst[2];
        #pragma unroll
        for (int qt = 0; qt < 2; ++qt) {
            int q = qt * 16 + c;
            float mm = -INFINITY;
            #pragma unroll
            for (int w = 0; w < 8; ++w) mm = fmaxf(mm, mbuf[w][q]);
            float ls = 0.f;
            #pragma unroll
            for (int w = 0; w < 8; ++w)
                ls += __builtin_amdgcn_exp2f(mbuf[w][q] - mm) * lbuf[w][q];
            fac[qt] = __builtin_amdgcn_exp2f(mrun[qt] - mm);
            lst[qt] = ls;
        }
        if (wave == 0 && lane < 16) {
            lsbuf[c]      = lst[0];
            lsbuf[16 + c] = lst[1];
        }
    }
    float facr[2][4];
    #pragma unroll
    for (int qt = 0; qt < 2; ++qt)
        #pragma unroll
        for (int r = 0; r < 4; ++r)
            facr[qt][r] = __shfl(fac[qt], 4 * g + r, 64);
    for (int w = 0; w < 8; ++w) {
        if (wave == w) {
            #pragma unroll
            for (int qt = 0; qt < 2; ++qt)
                #pragma unroll
                for (int dt = 0; dt < 8; ++dt)
                    #pragma unroll
                    for (int r = 0; r < 4; ++r)
                        obuf[qt * 16 + 4 * g + r][dt * 16 + c] += facr[qt][r] * acc[qt][dt][r];
        }
        __syncthreads();
    }
    const int qq = tid & 31;
    const int dg = tid >> 5;
    const float inv = 1.f / lsbuf[qq];
    #pragma unroll
    for (int i = 0; i < 8; ++i) {
        int d = dg * 8 + i;
        out[(size_t)d * NN + q0 + qq] = obuf[qq][d] * inv;
    }
}

extern "C" void kernel_launch(void* const* d_in, const int* in_sizes, int n_in,
                              void* d_out, int out_size, void* d_ws, size_t ws_size,
                              hipStream_t stream) {
    const float* Q = (const float*)d_in[0];
    const float* K = (const float*)d_in[1];
    const float* V = (const float*)d_in[2];
    float* out = (float*)d_out;

    if (ws_size < WS_NEED || d_ws == nullptr) {
        hipLaunchKernelGGL(attn_fwd_fb, dim3(NN / 32), dim3(512), 0, stream, Q, K, V, out);
        return;
    }
    char* ws = (char*)d_ws;
    char* kst = ws;
    float* mArr = (float*)(ws + WS_M);
    float* lArr = (float*)(ws + WS_L);
    float* opart = (float*)(ws + WS_OP);

    hipLaunchKernelGGL(attn_prep, dim3(NTILES), dim3(256), 0, stream, K, V, kst);
    hipLaunchKernelGGL(attn_main, dim3(KSPLIT * (NN / BQ)), dim3(256), 0, stream, Q, kst, mArr, lArr, opart);
    hipLaunchKernelGGL(attn_combine, dim3((NN / 256) * 8), dim3(256), 0, stream, opart, mArr, lArr, out);
}

// Round 4
// 71.155 us; speedup vs baseline: 6.7721x; 1.3036x over previous
//
#include <hip/hip_runtime.h>

#define NN 8192
#define DD 128
#define KSPLIT 16
#define KCHUNK (NN / KSPLIT)      // 512 k per WG
#define BK 32
#define NT (KCHUNK / BK)          // 16 tiles per WG
#define NTILES (NN / BK)          // 256 tiles total
#define TILE_B 16384              // Khi fp16 8K | Vp fp16 8K
#define OFF_V 8192
#define WAVES 4
#define BQ (WAVES * 32)           // 128 q per WG

// ws layout
#define WS_M   ((size_t)NTILES * TILE_B)                 // 4 MB kst
#define WS_L   (WS_M + (size_t)KSPLIT * NN * 4)
#define WS_OP  (WS_L + (size_t)KSPLIT * NN * 4)
#define WS_NEED (WS_OP + (size_t)KSPLIT * NN * DD * 2)   // ~38.8 MB

typedef __attribute__((ext_vector_type(8))) _Float16 f16x8;
typedef __attribute__((ext_vector_type(2))) _Float16 f16x2;
typedef __attribute__((ext_vector_type(8))) short bf16x8;
typedef __attribute__((ext_vector_type(4))) float f32x4;
typedef __attribute__((ext_vector_type(2))) float f32x2;
typedef __attribute__((ext_vector_type(16))) float f32x16;

static __device__ __forceinline__ unsigned short f2bf(float f) {
    union { float f; unsigned u; } v; v.f = f;
    return (unsigned short)((v.u + 0x7FFFu + ((v.u >> 16) & 1u)) >> 16);
}
static __device__ __forceinline__ float bf2f(unsigned short h) {
    union { unsigned u; float f; } v; v.u = ((unsigned)h) << 16;
    return v.f;
}
static __device__ __forceinline__ void gld_lds16(const char* g, char* l) {
    __builtin_amdgcn_global_load_lds(
        (const __attribute__((address_space(1))) unsigned*)g,
        (__attribute__((address_space(3))) unsigned*)l,
        16, 0, 0);
}

// ---------------- prep: build swizzled fp16 tile images ----------------
__global__ __launch_bounds__(256) void attn_prep(
    const float* __restrict__ Km, const float* __restrict__ Vm,
    char* __restrict__ kst)
{
    __shared__ __align__(16) char img[TILE_B];
    const int tt = blockIdx.x;
    const int tid = threadIdx.x;
    const int k0 = tt * BK;
    // K: logical [k][d] fp16, row 256B, swizzle ^((k&7)<<4)
    #pragma unroll
    for (int i = 0; i < 16; ++i) {
        int idx = i * 256 + tid;
        int d = idx >> 5, k = idx & 31;
        float kv = Km[(size_t)d * NN + k0 + k];
        int b = (k * 256 + d * 2) ^ ((k & 7) << 4);
        *(_Float16*)(img + b) = (_Float16)kv;
    }
    // V: logical [d][j] fp16, row 64B, swizzle ^((d&7)<<4)
    // j = s2*16 + h*8 + jj  maps actual k = (jj&3) + 4h + 8*(jj>>2) + 16*s2
    #pragma unroll
    for (int i = 0; i < 16; ++i) {
        int idx = i * 256 + tid;
        int d = idx >> 5, j = idx & 31;
        int kl = (j & 3) + 4 * ((j >> 3) & 1) + 8 * ((j >> 2) & 1) + 16 * (j >> 4);
        float vv = Vm[(size_t)d * NN + k0 + kl];
        int b = (d * 64 + j * 2) ^ ((d & 7) << 4);
        *(_Float16*)(img + OFF_V + b) = (_Float16)vv;
    }
    __syncthreads();
    float4* dst = (float4*)(kst + (size_t)tt * TILE_B);
    const float4* src = (const float4*)img;
    #pragma unroll
    for (int i = 0; i < 4; ++i) dst[i * 256 + tid] = src[i * 256 + tid];
}

// ---------------- main: flash attention, fp16 32x32 MFMA, split-k ----------------
__global__ __launch_bounds__(256, 3) void attn_main(
    const float* __restrict__ Qm, const char* __restrict__ kst,
    float* __restrict__ mArr, float* __restrict__ lArr,
    _Float16* __restrict__ opart)
{
    __shared__ __align__(16) char smem[2 * TILE_B];   // 32KB double buffer
    const int tid = threadIdx.x;
    const int wave = tid >> 6, lane = tid & 63;
    const int q31 = lane & 31;
    const int h = lane >> 5;
    const int swz = (lane & 7) << 4;
    const int ks = blockIdx.x & (KSPLIT - 1);
    const int qb = blockIdx.x >> 4;
    const int q0w = qb * BQ + wave * 32;
    const int qg = q0w + q31;
    const float LOG2E = 1.44269504088896340736f;

    // Q fragments: elem jj of qh[ds] = fp16(Q[16ds+8h+jj][qg]*log2e)
    f16x8 qh[8];
    #pragma unroll
    for (int ds = 0; ds < 8; ++ds)
        #pragma unroll
        for (int jj = 0; jj < 8; ++jj) {
            int d = 16 * ds + 8 * h + jj;
            qh[ds][jj] = (_Float16)(Qm[(size_t)d * NN + qg] * LOG2E);
        }

    f32x16 acc[4];
    #pragma unroll
    for (int dt = 0; dt < 4; ++dt)
        #pragma unroll
        for (int r = 0; r < 16; ++r) acc[dt][r] = 0.f;
    float mrun = -INFINITY, lrun = 0.f;

    // stage tile 0 -> buf 0
    {
        const char* gsrc = kst + (size_t)(ks * NT) * TILE_B + tid * 16;
        char* ldst = smem + tid * 16;
        #pragma unroll
        for (int i = 0; i < 4; ++i) gld_lds16(gsrc + i * 4096, ldst + i * 4096);
    }
    __syncthreads();

    for (int t = 0; t < NT; ++t) {
        const int cur = t & 1;
        const char* kb = smem + cur * TILE_B;

        if (t + 1 < NT) {   // prefetch next tile into other buffer
            const char* gsrc = kst + (size_t)(ks * NT + t + 1) * TILE_B + tid * 16;
            char* ldst = smem + (cur ^ 1) * TILE_B + tid * 16;
            #pragma unroll
            for (int i = 0; i < 4; ++i) gld_lds16(gsrc + i * 4096, ldst + i * 4096);
        }

        // ---- QK^T: S^T[k=32][q=32], single fp16, 8 d-steps of 16
        f32x16 T;
        #pragma unroll
        for (int r = 0; r < 16; ++r) T[r] = 0.f;
        __builtin_amdgcn_s_setprio(1);
        #pragma unroll
        for (int ds = 0; ds < 8; ++ds) {
            int off = ((q31 << 8) + ds * 32 + (h << 4)) ^ swz;
            f16x8 kh = *(const f16x8*)(kb + off);
            T = __builtin_amdgcn_mfma_f32_32x32x16_f16(kh, qh[ds], T, 0, 0, 0);
        }
        __builtin_amdgcn_s_setprio(0);

        // ---- online softmax (per-lane q; halves combined via xor32)
        float tmax = fmaxf(T[0], T[1]);
        #pragma unroll
        for (int r = 2; r < 16; ++r) tmax = fmaxf(tmax, T[r]);
        tmax = fmaxf(tmax, __shfl_xor(tmax, 32, 64));

        if (__any(tmax > mrun)) {    // defer-max: exact skip when sc==1 everywhere
            float mnew = fmaxf(mrun, tmax);
            float sc = __builtin_amdgcn_exp2f(mrun - mnew);
            mrun = mnew;
            lrun *= sc;
            #pragma unroll
            for (int dt = 0; dt < 4; ++dt)
                #pragma unroll
                for (int r = 0; r < 16; ++r) acc[dt][r] *= sc;
        }

        f16x8 pfrag[2];
        float psum = 0.f;
        #pragma unroll
        for (int s2 = 0; s2 < 2; ++s2)
            #pragma unroll
            for (int jj = 0; jj < 8; ++jj) {
                float p = __builtin_amdgcn_exp2f(T[8 * s2 + jj] - mrun);
                psum += p;
                pfrag[s2][jj] = (_Float16)p;
            }
        lrun += psum;

        // ---- PV: O^T[d][q] += V^T * P  (k-permuted contraction)
        __builtin_amdgcn_s_setprio(1);
        #pragma unroll
        for (int dt = 0; dt < 4; ++dt) {
            int vbase = (dt * 32 + q31) * 64 + (h << 4);
            #pragma unroll
            for (int s2 = 0; s2 < 2; ++s2) {
                f16x8 vb = *(const f16x8*)(kb + OFF_V + ((vbase + s2 * 32) ^ swz));
                acc[dt] = __builtin_amdgcn_mfma_f32_32x32x16_f16(vb, pfrag[s2], acc[dt], 0, 0, 0);
            }
        }
        __builtin_amdgcn_s_setprio(0);

        __syncthreads();
    }

    // ---- epilogue: partials to ws
    lrun += __shfl_xor(lrun, 32, 64);
    if (lane < 32) {
        mArr[ks * NN + qg] = mrun;
        lArr[ks * NN + qg] = lrun;
    }
    #pragma unroll
    for (int dt = 0; dt < 4; ++dt)
        #pragma unroll
        for (int r = 0; r < 16; ++r) {
            int d = dt * 32 + (r & 3) + 8 * (r >> 2) + 4 * h;
            opart[((size_t)ks * DD + d) * NN + qg] = (_Float16)acc[dt][r];
        }
}

// ---------------- combine: merge split-k partials ----------------
__global__ __launch_bounds__(256) void attn_combine(
    const _Float16* __restrict__ opart, const float* __restrict__ mArr,
    const float* __restrict__ lArr, float* __restrict__ out)
{
    const int tid = threadIdx.x;
    const int qg = blockIdx.x >> 3;            // 16 groups of 512 q
    const int dseg = (blockIdx.x & 7) * 16;
    const int q = qg * 512 + tid * 2;

    f32x2 mv[KSPLIT];
    float M0 = -INFINITY, M1 = -INFINITY;
    #pragma unroll
    for (int s = 0; s < KSPLIT; ++s) {
        mv[s] = *(const f32x2*)&mArr[(size_t)s * NN + q];
        M0 = fmaxf(M0, mv[s][0]);
        M1 = fmaxf(M1, mv[s][1]);
    }
    float L0 = 0.f, L1 = 0.f;
    f32x2 w[KSPLIT];
    #pragma unroll
    for (int s = 0; s < KSPLIT; ++s) {
        f32x2 lv = *(const f32x2*)&lArr[(size_t)s * NN + q];
        w[s][0] = __builtin_amdgcn_exp2f(mv[s][0] - M0);
        w[s][1] = __builtin_amdgcn_exp2f(mv[s][1] - M1);
        L0 += w[s][0] * lv[0];
        L1 += w[s][1] * lv[1];
    }
    float i0 = 1.f / L0, i1 = 1.f / L1;
    #pragma unroll
    for (int s = 0; s < KSPLIT; ++s) { w[s][0] *= i0; w[s][1] *= i1; }

    for (int dd = 0; dd < 16; ++dd) {
        int d = dseg + dd;
        float a0 = 0.f, a1 = 0.f;
        #pragma unroll
        for (int s = 0; s < KSPLIT; ++s) {
            f16x2 u = *(const f16x2*)&opart[((size_t)s * DD + d) * NN + q];
            a0 += w[s][0] * (float)u[0];
            a1 += w[s][1] * (float)u[1];
        }
        f32x2 o; o[0] = a0; o[1] = a1;
        *(f32x2*)&out[(size_t)d * NN + q] = o;
    }
}

// ---------------- fallback (round-1 kernel, used if ws too small) ----------------
__global__ __launch_bounds__(512, 2) void attn_fwd_fb(
    const float* __restrict__ Qm, const float* __restrict__ Km,
    const float* __restrict__ Vm, float* __restrict__ out)
{
    const int tid  = threadIdx.x;
    const int wave = tid >> 6;
    const int lane = tid & 63;
    const int c = lane & 15;
    const int g = lane >> 4;
    const int q0 = blockIdx.x * 32;
    const float LOG2E = 1.44269504088896340736f;

    bf16x8 qhi[2][4], qlo[2][4];
    #pragma unroll
    for (int qt = 0; qt < 2; ++qt)
        #pragma unroll
        for (int ds = 0; ds < 4; ++ds)
            #pragma unroll
            for (int jj = 0; jj < 8; ++jj) {
                int d = ds * 32 + 8 * g + jj;
                float qv = Qm[(size_t)d * NN + (q0 + qt * 16 + c)] * LOG2E;
                unsigned short hv = f2bf(qv);
                qhi[qt][ds][jj] = (short)hv;
                qlo[qt][ds][jj] = (short)f2bf(qv - bf2f(hv));
            }

    f32x4 acc[2][8];
    #pragma unroll
    for (int a = 0; a < 2; ++a)
        #pragma unroll
        for (int b = 0; b < 8; ++b)
            acc[a][b] = (f32x4){0.f, 0.f, 0.f, 0.f};
    float mrun[2] = {-INFINITY, -INFINITY};
    float lrun[2] = {0.f, 0.f};
    const int kw0 = wave * (NN / 8);

    for (int t = 0; t < (NN / 8) / 64; ++t) {
        const int k0 = kw0 + t * 64;
        f32x4 T[4][2];
        #pragma unroll
        for (int mkt = 0; mkt < 4; ++mkt) {
            T[mkt][0] = (f32x4){0.f, 0.f, 0.f, 0.f};
            T[mkt][1] = (f32x4){0.f, 0.f, 0.f, 0.f};
        }
        #pragma unroll
        for (int mkt = 0; mkt < 4; ++mkt) {
            const int kc = k0 + mkt * 16 + c;
            #pragma unroll
            for (int ds = 0; ds < 4; ++ds) {
                bf16x8 khi, klo;
                #pragma unroll
                for (int jj = 0; jj < 8; ++jj) {
                    int d = ds * 32 + 8 * g + jj;
                    float kv = Km[(size_t)d * NN + kc];
                    unsigned short hv = f2bf(kv);
                    khi[jj] = (short)hv;
                    klo[jj] = (short)f2bf(kv - bf2f(hv));
                }
                #pragma unroll
                for (int qt = 0; qt < 2; ++qt) {
                    T[mkt][qt] = __builtin_amdgcn_mfma_f32_16x16x32_bf16(khi, qhi[qt][ds], T[mkt][qt], 0, 0, 0);
                    T[mkt][qt] = __builtin_amdgcn_mfma_f32_16x16x32_bf16(khi, qlo[qt][ds], T[mkt][qt], 0, 0, 0);
                    T[mkt][qt] = __builtin_amdgcn_mfma_f32_16x16x32_bf16(klo, qhi[qt][ds], T[mkt][qt], 0, 0, 0);
                }
            }
        }
        bf16x8 pfrag[2][2];
        float scl[2];
        #pragma unroll
        for (int qt = 0; qt < 2; ++qt) {
            float tmax = T[0][qt][0];
            #pragma unroll
            for (int mkt = 0; mkt < 4; ++mkt)
                #pragma unroll
                for (int r = 0; r < 4; ++r)
                    tmax = fmaxf(tmax, T[mkt][qt][r]);
            tmax = fmaxf(tmax, __shfl_xor(tmax, 16, 64));
            tmax = fmaxf(tmax, __shfl_xor(tmax, 32, 64));
            float mnew = fmaxf(mrun[qt], tmax);
            float sc = __builtin_amdgcn_exp2f(mrun[qt] - mnew);
            mrun[qt] = mnew;
            lrun[qt] *= sc;
            scl[qt] = sc;
            #pragma unroll
            for (int s = 0; s < 2; ++s)
                #pragma unroll
                for (int hf = 0; hf < 2; ++hf) {
                    int mkt = 2 * s + hf;
                    #pragma unroll
                    for (int r = 0; r < 4; ++r) {
                        float p = __builtin_amdgcn_exp2f(T[mkt][qt][r] - mnew);
                        unsigned short pb = f2bf(p);
                        lrun[qt] += bf2f(pb);
                        pfrag[qt][s][hf * 4 + r] = (short)pb;
                    }
                }
        }
        #pragma unroll
        for (int qt = 0; qt < 2; ++qt)
            #pragma unroll
            for (int r = 0; r < 4; ++r) {
                float f = __shfl(scl[qt], 4 * g + r, 64);
                #pragma unroll
                for (int dt = 0; dt < 8; ++dt)
                    acc[qt][dt][r] *= f;
            }
        #pragma unroll
        for (int s = 0; s < 2; ++s)
            #pragma unroll
            for (int dt = 0; dt < 8; ++dt) {
                const float* vp = Vm + (size_t)(dt * 16 + c) * NN + (k0 + 32 * s + 4 * g);
                f32x4 v0 = *(const f32x4*)vp;
                f32x4 v1 = *(const f32x4*)(vp + 16);
                bf16x8 vb;
                #pragma unroll
                for (int e = 0; e < 4; ++e) {
                    vb[e]     = (short)f2bf(v0[e]);
                    vb[4 + e] = (short)f2bf(v1[e]);
                }
                #pragma unroll
                for (int qt = 0; qt < 2; ++qt)
                    acc[qt][dt] = __builtin_amdgcn_mfma_f32_16x16x32_bf16(pfrag[qt][s], vb, acc[qt][dt], 0, 0, 0);
            }
    }

    __shared__ float obuf[32][DD + 4];
    __shared__ float mbuf[8][32];
    __shared__ float lbuf[8][32];
    __shared__ float lsbuf[32];
    #pragma unroll
    for (int qt = 0; qt < 2; ++qt) {
        lrun[qt] += __shfl_xor(lrun[qt], 16, 64);
        lrun[qt] += __shfl_xor(lrun[qt], 32, 64);
    }
    if (lane < 16) {
        mbuf[wave][c]      = mrun[0];
        mbuf[wave][16 + c] = mrun[1];
        lbuf[wave][c]      = lrun[0];
        lbuf[wave][16 + c] = lrun[1];
    }
    for (int i = tid; i < 32 * (DD + 4); i += 512)
        (&obuf[0][0])[i] = 0.f;
    __syncthreads();
    float fac[2];
    {
        float lst[2];
        #pragma unroll
        for (int qt = 0; qt < 2; ++qt) {
            int q = qt * 16 + c;
            float mm = -INFINITY;
            #pragma unroll
            for (int w = 0; w < 8; ++w) mm = fmaxf(mm, mbuf[w][q]);
            float ls = 0.f;
            #pragma unroll
            for (int w = 0; w < 8; ++w)
                ls += __builtin_amdgcn_exp2f(mbuf[w][q] - mm) * lbuf[w][q];
            fac[qt] = __builtin_amdgcn_exp2f(mrun[qt] - mm);
            lst[qt] = ls;
        }
        if (wave == 0 && lane < 16) {
            lsbuf[c]      = lst[0];
            lsbuf[16 + c] = lst[1];
        }
    }
    float facr[2][4];
    #pragma unroll
    for (int qt = 0; qt < 2; ++qt)
        #pragma unroll
        for (int r = 0; r < 4; ++r)
            facr[qt][r] = __shfl(fac[qt], 4 * g + r, 64);
    for (int w = 0; w < 8; ++w) {
        if (wave == w) {
            #pragma unroll
            for (int qt = 0; qt < 2; ++qt)
                #pragma unroll
                for (int dt = 0; dt < 8; ++dt)
                    #pragma unroll
                    for (int r = 0; r < 4; ++r)
                        obuf[qt * 16 + 4 * g + r][dt * 16 + c] += facr[qt][r] * acc[qt][dt][r];
        }
        __syncthreads();
    }
    const int qq = tid & 31;
    const int dg = tid >> 5;
    const float inv = 1.f / lsbuf[qq];
    #pragma unroll
    for (int i = 0; i < 8; ++i) {
        int d = dg * 8 + i;
        out[(size_t)d * NN + q0 + qq] = obuf[qq][d] * inv;
    }
}

extern "C" void kernel_launch(void* const* d_in, const int* in_sizes, int n_in,
                              void* d_out, int out_size, void* d_ws, size_t ws_size,
                              hipStream_t stream) {
    const float* Q = (const float*)d_in[0];
    const float* K = (const float*)d_in[1];
    const float* V = (const float*)d_in[2];
    float* out = (float*)d_out;

    if (ws_size < WS_NEED || d_ws == nullptr) {
        hipLaunchKernelGGL(attn_fwd_fb, dim3(NN / 32), dim3(512), 0, stream, Q, K, V, out);
        return;
    }
    char* ws = (char*)d_ws;
    char* kst = ws;
    float* mArr = (float*)(ws + WS_M);
    float* lArr = (float*)(ws + WS_L);
    _Float16* opart = (_Float16*)(ws + WS_OP);

    hipLaunchKernelGGL(attn_prep, dim3(NTILES), dim3(256), 0, stream, K, V, kst);
    hipLaunchKernelGGL(attn_main, dim3(KSPLIT * (NN / BQ)), dim3(256), 0, stream, Q, kst, mArr, lArr, opart);
    hipLaunchKernelGGL(attn_combine, dim3((NN / 512) * 8), dim3(256), 0, stream, opart, mArr, lArr, out);
}

// Round 6
// 65.627 us; speedup vs baseline: 7.3426x; 1.0842x over previous
//
#include <hip/hip_runtime.h>

#define NN 8192
#define DD 128
#define KSPLIT 8
#define KCHUNK (NN / KSPLIT)      // 1024 k per WG
#define BK 32
#define NT (KCHUNK / BK)          // 32 tiles per WG
#define NTILES (NN / BK)          // 256 tiles total
#define TILE_B 16384              // K fp16 8K | Vp fp16 8K
#define OFF_V 8192
#define WAVES 4
#define BQ (WAVES * 32)           // 128 q per WG

// ws layout
#define WS_M   ((size_t)NTILES * TILE_B)                 // 4 MB kst
#define WS_L   (WS_M + (size_t)KSPLIT * NN * 4)
#define WS_OP  (WS_L + (size_t)KSPLIT * NN * 4)
#define WS_NEED (WS_OP + (size_t)KSPLIT * NN * DD * 2)   // ~21.3 MB

typedef __attribute__((ext_vector_type(8))) _Float16 f16x8;
typedef __attribute__((ext_vector_type(2))) _Float16 f16x2;
typedef __attribute__((ext_vector_type(2))) __fp16 fp16v2;
typedef __attribute__((ext_vector_type(8))) short bf16x8;
typedef __attribute__((ext_vector_type(4))) float f32x4;
typedef __attribute__((ext_vector_type(2))) float f32x2;
typedef __attribute__((ext_vector_type(16))) float f32x16;

static __device__ __forceinline__ unsigned short f2bf(float f) {
    union { float f; unsigned u; } v; v.f = f;
    return (unsigned short)((v.u + 0x7FFFu + ((v.u >> 16) & 1u)) >> 16);
}
static __device__ __forceinline__ float bf2f(unsigned short h) {
    union { unsigned u; float f; } v; v.u = ((unsigned)h) << 16;
    return v.f;
}
static __device__ __forceinline__ void gld_lds16(const char* g, char* l) {
    __builtin_amdgcn_global_load_lds(
        (const __attribute__((address_space(1))) unsigned*)g,
        (__attribute__((address_space(3))) unsigned*)l,
        16, 0, 0);
}

// ---------------- prep: build swizzled fp16 tile images ----------------
__global__ __launch_bounds__(256) void attn_prep(
    const float* __restrict__ Km, const float* __restrict__ Vm,
    char* __restrict__ kst)
{
    __shared__ __align__(16) char img[TILE_B];
    const int tt = blockIdx.x;
    const int tid = threadIdx.x;
    const int k0 = tt * BK;
    // K: logical [k][d] fp16, row 256B, swizzle ^((k&15)<<4)  (16-slot XOR)
    #pragma unroll
    for (int i = 0; i < 16; ++i) {
        int idx = i * 256 + tid;
        int d = idx >> 5, k = idx & 31;
        float kv = Km[(size_t)d * NN + k0 + k];
        int b = (k * 256 + d * 2) ^ ((k & 15) << 4);
        *(_Float16*)(img + b) = (_Float16)kv;
    }
    // V: logical [d][j] fp16, row 64B, swizzle ^((d&7)<<4)
    // j = s2*16 + h*8 + jj  maps actual k = (jj&3) + 4h + 8*(jj>>2) + 16*s2
    #pragma unroll
    for (int i = 0; i < 16; ++i) {
        int idx = i * 256 + tid;
        int d = idx >> 5, j = idx & 31;
        int kl = (j & 3) + 4 * ((j >> 3) & 1) + 8 * ((j >> 2) & 1) + 16 * (j >> 4);
        float vv = Vm[(size_t)d * NN + k0 + kl];
        int b = (d * 64 + j * 2) ^ ((d & 7) << 4);
        *(_Float16*)(img + OFF_V + b) = (_Float16)vv;
    }
    __syncthreads();
    float4* dst = (float4*)(kst + (size_t)tt * TILE_B);
    const float4* src = (const float4*)img;
    #pragma unroll
    for (int i = 0; i < 4; ++i) dst[i * 256 + tid] = src[i * 256 + tid];
}

// ---------------- main: pipelined flash attention, fp16 32x32 MFMA ----------------
__global__ __launch_bounds__(256, 2) void attn_main(
    const float* __restrict__ Qm, const char* __restrict__ kst,
    float* __restrict__ mArr, float* __restrict__ lArr,
    _Float16* __restrict__ opart)
{
    __shared__ __align__(16) char smem[4 * TILE_B];   // 64KB, 4-deep ring
    const int tid = threadIdx.x;
    const int wave = tid >> 6, lane = tid & 63;
    const int q31 = lane & 31;
    const int h = lane >> 5;
    const int kswz = (q31 & 15) << 4;
    const int vswz = (lane & 7) << 4;
    const int ks = blockIdx.x & (KSPLIT - 1);
    const int qb = blockIdx.x >> 3;
    const int q0w = qb * BQ + wave * 32;
    const int qg = q0w + q31;
    const float LOG2E = 1.44269504088896340736f;

    // Q fragments: elem jj of qh[ds] = fp16(Q[16ds+8h+jj][qg]*log2e)
    f16x8 qh[8];
    #pragma unroll
    for (int ds = 0; ds < 8; ++ds)
        #pragma unroll
        for (int jj = 0; jj < 8; ++jj) {
            int d = 16 * ds + 8 * h + jj;
            qh[ds][jj] = (_Float16)(Qm[(size_t)d * NN + qg] * LOG2E);
        }

    f32x16 acc[4];
    #pragma unroll
    for (int dt = 0; dt < 4; ++dt)
        #pragma unroll
        for (int r = 0; r < 16; ++r) acc[dt][r] = 0.f;
    float mrun = -INFINITY, lrun = 0.f;

    const char* kwg = kst + (size_t)(ks * NT) * TILE_B + tid * 16;

#define STAGE(T, BI)                                                        \
    {                                                                       \
        const char* gs_ = kwg + (size_t)(T) * TILE_B;                       \
        char* ld_ = smem + (BI) * TILE_B + tid * 16;                        \
        gld_lds16(gs_,          ld_);                                       \
        gld_lds16(gs_ + 4096,   ld_ + 4096);                                \
        gld_lds16(gs_ + 8192,   ld_ + 8192);                                \
        gld_lds16(gs_ + 12288,  ld_ + 12288);                               \
    }

#define QKSTEP(BI, TDST)                                                    \
    {                                                                       \
        const char* kb_ = smem + (BI) * TILE_B;                             \
        _Pragma("unroll")                                                   \
        for (int r = 0; r < 16; ++r) TDST[r] = 0.f;                         \
        __builtin_amdgcn_s_setprio(1);                                      \
        _Pragma("unroll")                                                   \
        for (int ds = 0; ds < 8; ++ds) {                                    \
            int off_ = ((q31 << 8) + ds * 32 + (h << 4)) ^ kswz;            \
            f16x8 kh_ = *(const f16x8*)(kb_ + off_);                        \
            TDST = __builtin_amdgcn_mfma_f32_32x32x16_f16(kh_, qh[ds], TDST, 0, 0, 0); \
        }                                                                   \
        __builtin_amdgcn_s_setprio(0);                                      \
    }

#define SMPV(BI, TCUR)                                                      \
    {                                                                       \
        float a0_ = fmaxf(fmaxf(TCUR[0], TCUR[1]), TCUR[2]);                \
        float a1_ = fmaxf(fmaxf(TCUR[3], TCUR[4]), TCUR[5]);                \
        float a2_ = fmaxf(fmaxf(TCUR[6], TCUR[7]), TCUR[8]);                \
        float a3_ = fmaxf(fmaxf(TCUR[9], TCUR[10]), TCUR[11]);              \
        float a4_ = fmaxf(fmaxf(TCUR[12], TCUR[13]), TCUR[14]);             \
        float tmax_ = fmaxf(fmaxf(fmaxf(a0_, a1_), a2_),                    \
                            fmaxf(fmaxf(a3_, a4_), TCUR[15]));              \
        tmax_ = fmaxf(tmax_, __shfl_xor(tmax_, 32, 64));                    \
        if (__any(tmax_ > mrun)) {                                          \
            float mnew_ = fmaxf(mrun, tmax_);                               \
            float sc_ = __builtin_amdgcn_exp2f(mrun - mnew_);               \
            mrun = mnew_; lrun *= sc_;                                      \
            _Pragma("unroll")                                               \
            for (int dt = 0; dt < 4; ++dt)                                  \
                _Pragma("unroll")                                           \
                for (int r = 0; r < 16; ++r) acc[dt][r] *= sc_;             \
        }                                                                   \
        float p_[16];                                                       \
        _Pragma("unroll")                                                   \
        for (int r = 0; r < 16; ++r)                                        \
            p_[r] = __builtin_amdgcn_exp2f(TCUR[r] - mrun);                 \
        float s0_ = (p_[0] + p_[1]) + (p_[2] + p_[3]);                      \
        float s1_ = (p_[4] + p_[5]) + (p_[6] + p_[7]);                      \
        float s2_ = (p_[8] + p_[9]) + (p_[10] + p_[11]);                    \
        float s3_ = (p_[12] + p_[13]) + (p_[14] + p_[15]);                  \
        lrun += (s0_ + s1_) + (s2_ + s3_);                                  \
        union { f16x8 v[2]; fp16v2 h2[8]; } pu_;                            \
        _Pragma("unroll")                                                   \
        for (int r = 0; r < 8; ++r)                                         \
            pu_.h2[r] = __builtin_amdgcn_cvt_pkrtz(p_[2 * r], p_[2 * r + 1]); \
        const char* vb_ = smem + (BI) * TILE_B + OFF_V;                     \
        __builtin_amdgcn_s_setprio(1);                                      \
        _Pragma("unroll")                                                   \
        for (int dt = 0; dt < 4; ++dt) {                                    \
            int vbase_ = (dt * 32 + q31) * 64 + (h << 4);                   \
            f16x8 v0_ = *(const f16x8*)(vb_ + ((vbase_) ^ vswz));           \
            f16x8 v1_ = *(const f16x8*)(vb_ + ((vbase_ + 32) ^ vswz));      \
            acc[dt] = __builtin_amdgcn_mfma_f32_32x32x16_f16(v0_, pu_.v[0], acc[dt], 0, 0, 0); \
            acc[dt] = __builtin_amdgcn_mfma_f32_32x32x16_f16(v1_, pu_.v[1], acc[dt], 0, 0, 0); \
        }                                                                   \
        __builtin_amdgcn_s_setprio(0);                                      \
    }

#define STEP(I, TCUR, TNXT)                                                 \
    {                                                                       \
        const int t_ = tb + (I);                                            \
        if (t_ + 2 < NT) STAGE(t_ + 2, ((I) + 2) & 3);                      \
        if (t_ + 1 < NT) QKSTEP(((I) + 1) & 3, TNXT);                       \
        SMPV((I) & 3, TCUR);                                                \
        __syncthreads();                                                    \
    }

    // prologue: stage tiles 0,1
    STAGE(0, 0);
    STAGE(1, 1);
    __syncthreads();
    f32x16 TA, TB;
    QKSTEP(0, TA);

    for (int tb = 0; tb < NT; tb += 4) {
        STEP(0, TA, TB);
        STEP(1, TB, TA);
        STEP(2, TA, TB);
        STEP(3, TB, TA);
    }

    // ---- epilogue: partials to ws
    lrun += __shfl_xor(lrun, 32, 64);
    if (lane < 32) {
        mArr[ks * NN + qg] = mrun;
        lArr[ks * NN + qg] = lrun;
    }
    #pragma unroll
    for (int dt = 0; dt < 4; ++dt)
        #pragma unroll
        for (int r = 0; r < 16; ++r) {
            int d = dt * 32 + (r & 3) + 8 * (r >> 2) + 4 * h;
            opart[((size_t)ks * DD + d) * NN + qg] = (_Float16)acc[dt][r];
        }
#undef STAGE
#undef QKSTEP
#undef SMPV
#undef STEP
}

// ---------------- combine: merge split-k partials ----------------
__global__ __launch_bounds__(256) void attn_combine(
    const _Float16* __restrict__ opart, const float* __restrict__ mArr,
    const float* __restrict__ lArr, float* __restrict__ out)
{
    const int tid = threadIdx.x;
    const int qg = blockIdx.x >> 3;            // groups of 512 q
    const int dseg = (blockIdx.x & 7) * 16;
    const int q = qg * 512 + tid * 2;

    f32x2 mv[KSPLIT];
    float M0 = -INFINITY, M1 = -INFINITY;
    #pragma unroll
    for (int s = 0; s < KSPLIT; ++s) {
        mv[s] = *(const f32x2*)&mArr[(size_t)s * NN + q];
        M0 = fmaxf(M0, mv[s][0]);
        M1 = fmaxf(M1, mv[s][1]);
    }
    float L0 = 0.f, L1 = 0.f;
    f32x2 w[KSPLIT];
    #pragma unroll
    for (int s = 0; s < KSPLIT; ++s) {
        f32x2 lv = *(const f32x2*)&lArr[(size_t)s * NN + q];
        w[s][0] = __builtin_amdgcn_exp2f(mv[s][0] - M0);
        w[s][1] = __builtin_amdgcn_exp2f(mv[s][1] - M1);
        L0 += w[s][0] * lv[0];
        L1 += w[s][1] * lv[1];
    }
    float i0 = 1.f / L0, i1 = 1.f / L1;
    #pragma unroll
    for (int s = 0; s < KSPLIT; ++s) { w[s][0] *= i0; w[s][1] *= i1; }

    for (int dd = 0; dd < 16; ++dd) {
        int d = dseg + dd;
        float a0 = 0.f, a1 = 0.f;
        #pragma unroll
        for (int s = 0; s < KSPLIT; ++s) {
            f16x2 u = *(const f16x2*)&opart[((size_t)s * DD + d) * NN + q];
            a0 += w[s][0] * (float)u[0];
            a1 += w[s][1] * (float)u[1];
        }
        f32x2 o; o[0] = a0; o[1] = a1;
        *(f32x2*)&out[(size_t)d * NN + q] = o;
    }
}

// ---------------- fallback (round-1 kernel, used if ws too small) ----------------
__global__ __launch_bounds__(512, 2) void attn_fwd_fb(
    const float* __restrict__ Qm, const float* __restrict__ Km,
    const float* __restrict__ Vm, float* __restrict__ out)
{
    const int tid  = threadIdx.x;
    const int wave = tid >> 6;
    const int lane = tid & 63;
    const int c = lane & 15;
    const int g = lane >> 4;
    const int q0 = blockIdx.x * 32;
    const float LOG2E = 1.44269504088896340736f;

    bf16x8 qhi[2][4], qlo[2][4];
    #pragma unroll
    for (int qt = 0; qt < 2; ++qt)
        #pragma unroll
        for (int ds = 0; ds < 4; ++ds)
            #pragma unroll
            for (int jj = 0; jj < 8; ++jj) {
                int d = ds * 32 + 8 * g + jj;
                float qv = Qm[(size_t)d * NN + (q0 + qt * 16 + c)] * LOG2E;
                unsigned short hv = f2bf(qv);
                qhi[qt][ds][jj] = (short)hv;
                qlo[qt][ds][jj] = (short)f2bf(qv - bf2f(hv));
            }

    f32x4 acc[2][8];
    #pragma unroll
    for (int a = 0; a < 2; ++a)
        #pragma unroll
        for (int b = 0; b < 8; ++b)
            acc[a][b] = (f32x4){0.f, 0.f, 0.f, 0.f};
    float mrun[2] = {-INFINITY, -INFINITY};
    float lrun[2] = {0.f, 0.f};
    const int kw0 = wave * (NN / 8);

    for (int t = 0; t < (NN / 8) / 64; ++t) {
        const int k0 = kw0 + t * 64;
        f32x4 T[4][2];
        #pragma unroll
        for (int mkt = 0; mkt < 4; ++mkt) {
            T[mkt][0] = (f32x4){0.f, 0.f, 0.f, 0.f};
            T[mkt][1] = (f32x4){0.f, 0.f, 0.f, 0.f};
        }
        #pragma unroll
        for (int mkt = 0; mkt < 4; ++mkt) {
            const int kc = k0 + mkt * 16 + c;
            #pragma unroll
            for (int ds = 0; ds < 4; ++ds) {
                bf16x8 khi, klo;
                #pragma unroll
                for (int jj = 0; jj < 8; ++jj) {
                    int d = ds * 32 + 8 * g + jj;
                    float kv = Km[(size_t)d * NN + kc];
                    unsigned short hv = f2bf(kv);
                    khi[jj] = (short)hv;
                    klo[jj] = (short)f2bf(kv - bf2f(hv));
                }
                #pragma unroll
                for (int qt = 0; qt < 2; ++qt) {
                    T[mkt][qt] = __builtin_amdgcn_mfma_f32_16x16x32_bf16(khi, qhi[qt][ds], T[mkt][qt], 0, 0, 0);
                    T[mkt][qt] = __builtin_amdgcn_mfma_f32_16x16x32_bf16(khi, qlo[qt][ds], T[mkt][qt], 0, 0, 0);
                    T[mkt][qt] = __builtin_amdgcn_mfma_f32_16x16x32_bf16(klo, qhi[qt][ds], T[mkt][qt], 0, 0, 0);
                }
            }
        }
        bf16x8 pfrag[2][2];
        float scl[2];
        #pragma unroll
        for (int qt = 0; qt < 2; ++qt) {
            float tmax = T[0][qt][0];
            #pragma unroll
            for (int mkt = 0; mkt < 4; ++mkt)
                #pragma unroll
                for (int r = 0; r < 4; ++r)
                    tmax = fmaxf(tmax, T[mkt][qt][r]);
            tmax = fmaxf(tmax, __shfl_xor(tmax, 16, 64));
            tmax = fmaxf(tmax, __shfl_xor(tmax, 32, 64));
            float mnew = fmaxf(mrun[qt], tmax);
            float sc = __builtin_amdgcn_exp2f(mrun[qt] - mnew);
            mrun[qt] = mnew;
            lrun[qt] *= sc;
            scl[qt] = sc;
            #pragma unroll
            for (int s = 0; s < 2; ++s)
                #pragma unroll
                for (int hf = 0; hf < 2; ++hf) {
                    int mkt = 2 * s + hf;
                    #pragma unroll
                    for (int r = 0; r < 4; ++r) {
                        float p = __builtin_amdgcn_exp2f(T[mkt][qt][r] - mnew);
                        unsigned short pb = f2bf(p);
                        lrun[qt] += bf2f(pb);
                        pfrag[qt][s][hf * 4 + r] = (short)pb;
                    }
                }
        }
        #pragma unroll
        for (int qt = 0; qt < 2; ++qt)
            #pragma unroll
            for (int r = 0; r < 4; ++r) {
                float f = __shfl(scl[qt], 4 * g + r, 64);
                #pragma unroll
                for (int dt = 0; dt < 8; ++dt)
                    acc[qt][dt][r] *= f;
            }
        #pragma unroll
        for (int s = 0; s < 2; ++s)
            #pragma unroll
            for (int dt = 0; dt < 8; ++dt) {
                const float* vp = Vm + (size_t)(dt * 16 + c) * NN + (k0 + 32 * s + 4 * g);
                f32x4 v0 = *(const f32x4*)vp;
                f32x4 v1 = *(const f32x4*)(vp + 16);
                bf16x8 vb;
                #pragma unroll
                for (int e = 0; e < 4; ++e) {
                    vb[e]     = (short)f2bf(v0[e]);
                    vb[4 + e] = (short)f2bf(v1[e]);
                }
                #pragma unroll
                for (int qt = 0; qt < 2; ++qt)
                    acc[qt][dt] = __builtin_amdgcn_mfma_f32_16x16x32_bf16(pfrag[qt][s], vb, acc[qt][dt], 0, 0, 0);
            }
    }

    __shared__ float obuf[32][DD + 4];
    __shared__ float mbuf[8][32];
    __shared__ float lbuf[8][32];
    __shared__ float lsbuf[32];
    #pragma unroll
    for (int qt = 0; qt < 2; ++qt) {
        lrun[qt] += __shfl_xor(lrun[qt], 16, 64);
        lrun[qt] += __shfl_xor(lrun[qt], 32, 64);
    }
    if (lane < 16) {
        mbuf[wave][c]      = mrun[0];
        mbuf[wave][16 + c] = mrun[1];
        lbuf[wave][c]      = lrun[0];
        lbuf[wave][16 + c] = lrun[1];
    }
    for (int i = tid; i < 32 * (DD + 4); i += 512)
        (&obuf[0][0])[i] = 0.f;
    __syncthreads();
    float fac[2];
    {
        float lst[2];
        #pragma unroll
        for (int qt = 0; qt < 2; ++qt) {
            int q = qt * 16 + c;
            float mm = -INFINITY;
            #pragma unroll
            for (int w = 0; w < 8; ++w) mm = fmaxf(mm, mbuf[w][q]);
            float ls = 0.f;
            #pragma unroll
            for (int w = 0; w < 8; ++w)
                ls += __builtin_amdgcn_exp2f(mbuf[w][q] - mm) * lbuf[w][q];
            fac[qt] = __builtin_amdgcn_exp2f(mrun[qt] - mm);
            lst[qt] = ls;
        }
        if (wave == 0 && lane < 16) {
            lsbuf[c]      = lst[0];
            lsbuf[16 + c] = lst[1];
        }
    }
    float facr[2][4];
    #pragma unroll
    for (int qt = 0; qt < 2; ++qt)
        #pragma unroll
        for (int r = 0; r < 4; ++r)
            facr[qt][r] = __shfl(fac[qt], 4 * g + r, 64);
    for (int w = 0; w < 8; ++w) {
        if (wave == w) {
            #pragma unroll
            for (int qt = 0; qt < 2; ++qt)
                #pragma unroll
                for (int dt = 0; dt < 8; ++dt)
                    #pragma unroll
                    for (int r = 0; r < 4; ++r)
                        obuf[qt * 16 + 4 * g + r][dt * 16 + c] += facr[qt][r] * acc[qt][dt][r];
        }
        __syncthreads();
    }
    const int qq = tid & 31;
    const int dg = tid >> 5;
    const float inv = 1.f / lsbuf[qq];
    #pragma unroll
    for (int i = 0; i < 8; ++i) {
        int d = dg * 8 + i;
        out[(size_t)d * NN + q0 + qq] = obuf[qq][d] * inv;
    }
}

extern "C" void kernel_launch(void* const* d_in, const int* in_sizes, int n_in,
                              void* d_out, int out_size, void* d_ws, size_t ws_size,
                              hipStream_t stream) {
    const float* Q = (const float*)d_in[0];
    const float* K = (const float*)d_in[1];
    const float* V = (const float*)d_in[2];
    float* out = (float*)d_out;

    if (ws_size < WS_NEED || d_ws == nullptr) {
        hipLaunchKernelGGL(attn_fwd_fb, dim3(NN / 32), dim3(512), 0, stream, Q, K, V, out);
        return;
    }
    char* ws = (char*)d_ws;
    char* kst = ws;
    float* mArr = (float*)(ws + WS_M);
    float* lArr = (float*)(ws + WS_L);
    _Float16* opart = (_Float16*)(ws + WS_OP);

    hipLaunchKernelGGL(attn_prep, dim3(NTILES), dim3(256), 0, stream, K, V, kst);
    hipLaunchKernelGGL(attn_main, dim3(KSPLIT * (NN / BQ)), dim3(256), 0, stream, Q, kst, mArr, lArr, opart);
    hipLaunchKernelGGL(attn_combine, dim3((NN / 512) * 8), dim3(256), 0, stream, opart, mArr, lArr, out);
}